// Round 4
// baseline (589.390 us; speedup 1.0000x reference)
//
#include <hip/hip_runtime.h>

typedef unsigned int u32;

#define BS    16
#define HDIM  2048
#define QL    768
#define KVL   512
#define DR    64
#define DN    128
#define NH    16
#define NIH   8
#define IDXD  128
#define BLK   128
#define BPS   32
#define MAXKV 4096
#define TOPK  1024

// ---------- 1. fused down-proj partials: [0:768|768:1344|1344:1472] ----------
// grid (23, 4 k-splits), 512 thr
__global__ void k_dproj(const float* __restrict__ x, const float* __restrict__ w_dq,
                        const float* __restrict__ w_dkv, const float* __restrict__ w_ik,
                        float* __restrict__ dpart){
  int tt = blockIdx.x, ks = blockIdx.y, t = threadIdx.x;
  __shared__ float xs[16*512];
  for (int idx=t; idx<16*512; idx+=512){
    int bb = idx>>9, kk = idx&511;
    xs[idx] = x[bb*HDIM + ks*512 + kk];
  }
  const float* wp; int ld, c0, gbase;
  if (tt < 12){ wp = w_dq;  ld = 768; c0 = tt*64;      gbase = 0; }
  else if (tt < 21){ wp = w_dkv; ld = 576; c0 = (tt-12)*64; gbase = 768; }
  else { wp = w_ik;  ld = 128; c0 = (tt-21)*64; gbase = 1344; }
  int lane = t&63, bg = t>>6;          // bg 0..7, 2 batches each
  int col = c0 + lane;
  __syncthreads();
  float a0=0.f, a1=0.f;
  const float* wb = wp + (size_t)(ks*512)*ld + col;
  const float* xb = &xs[bg*1024];
  for (int kk=0; kk<512; kk++){
    float wv = wb[(size_t)kk*ld];
    a0 += xb[kk]*wv; a1 += xb[512+kk]*wv;
  }
  int gcol = gbase + col;
  float* dp = dpart + (size_t)(ks*16)*1472;
  dp[(bg*2+0)*1472 + gcol] = a0;
  dp[(bg*2+1)*1472 + gcol] = a1;
}

// ---------- 2. finalize norms + cache scatter ----------
__global__ void k_dfin(const float* __restrict__ dpart, const float* __restrict__ g_cq,
                       const float* __restrict__ g_ckv, const float* __restrict__ sinp,
                       const float* __restrict__ cosp, const float* __restrict__ g_ik,
                       const float* __restrict__ b_ik, const int* __restrict__ cidx,
                       float* __restrict__ cq, float* __restrict__ kvc,
                       float* __restrict__ krc, float* __restrict__ ikc){
  int b = blockIdx.x, t = threadIdx.x;   // 256
  __shared__ float val[1472];
  __shared__ float red[256];
  for (int c=t; c<1472; c+=256){
    float s = 0.f;
    for (int ks2=0; ks2<4; ks2++) s += dpart[((size_t)ks2*16+b)*1472 + c];
    val[c] = s;
  }
  __syncthreads();
  float c0v = val[t], c1v = val[t+256], c2v = val[t+512];
  red[t] = c0v*c0v + c1v*c1v + c2v*c2v;
  __syncthreads();
  for (int s=128;s>0;s>>=1){ if(t<s) red[t]+=red[t+s]; __syncthreads(); }
  float scq = 1.0f/sqrtf(red[0]/(float)QL + 1e-6f);
  __syncthreads();
  float v0 = val[768+t], v1 = val[1024+t];
  red[t] = v0*v0 + v1*v1;
  __syncthreads();
  for (int s=128;s>0;s>>=1){ if(t<s) red[t]+=red[t+s]; __syncthreads(); }
  float sckv = 1.0f/sqrtf(red[0]/(float)KVL + 1e-6f);
  __syncthreads();
  red[t] = (t<128)? val[1344+t] : 0.f;
  __syncthreads();
  for (int s=128;s>0;s>>=1){ if(t<s) red[t]+=red[t+s]; __syncthreads(); }
  float mean = red[0]/(float)IDXD;
  __syncthreads();
  float cc = (t<128)? (val[1344+t]-mean) : 0.f;
  red[t] = cc*cc;
  __syncthreads();
  for (int s=128;s>0;s>>=1){ if(t<s) red[t]+=red[t+s]; __syncthreads(); }
  float var = red[0]/(float)IDXD;
  int ci = cidx[b];
  cq[b*QL+t]     = c0v*scq*g_cq[t];
  cq[b*QL+t+256] = c1v*scq*g_cq[t+256];
  cq[b*QL+t+512] = c2v*scq*g_cq[t+512];
  kvc[(size_t)ci*KVL + t]     = v0*sckv*g_ckv[t];
  kvc[(size_t)ci*KVL + t+256] = v1*sckv*g_ckv[t+256];
  if (t<DR){
    float v = val[1280+t];
    float rot = (t<32)? -val[1280+t+32] : val[1280+t-32];
    krc[(size_t)ci*DR + t] = v*cosp[b*DR+t] + rot*sinp[b*DR+t];
  }
  if (t<IDXD){
    ikc[(size_t)ci*IDXD + t] = cc/sqrtf(var+1e-6f)*g_ik[t] + b_ik[t];
  }
}

// ---------- 3. fused q-level proj ----------
// grid 65, 512 thr
__global__ void k_qall(const float* __restrict__ cq, const float* __restrict__ w_uq,
                       const float* __restrict__ w_qb, const float* __restrict__ w_pj,
                       const float* __restrict__ sinp, const float* __restrict__ cosp,
                       float* __restrict__ qn, float* __restrict__ qp,
                       float* __restrict__ qi, float* __restrict__ hw){
  int tt = blockIdx.x, t = threadIdx.x;
  __shared__ float xs[16*768];     // 48 KB
  __shared__ float tile[16*64];    // 4 KB
  for (int idx=t; idx<16*768; idx+=512) xs[idx] = cq[idx];
  const float* wp; int ld, c0, kind;
  if (tt < 48){ wp=w_uq; ld=3072; c0=tt*64; kind = ((tt%3)==2)?1:0; }
  else if (tt < 64){ wp=w_qb; ld=1024; c0=(tt-48)*64; kind=2; }
  else { wp=w_pj; ld=8; c0=0; kind=3; }
  int lane = t&63, bg = t>>6;          // bg 0..7, 2 batches each
  int col = c0 + lane;
  __syncthreads();
  float a0=0.f, a1=0.f;
  if (kind!=3 || lane<8){
    const float* wb = wp + col;
    const float* xb = &xs[bg*1536];
    for (int k=0;k<768;k++){
      float wv = wb[(size_t)k*ld];
      a0 += xb[k]*wv; a1 += xb[768+k]*wv;
    }
  }
  if (kind==0){
    int h = col/192, j = col%192;      // j < 128
    qn[((bg*2+0)*NH+h)*DN + j] = a0;
    qn[((bg*2+1)*NH+h)*DN + j] = a1;
  } else if (kind==1){
    int h = tt/3, d = lane;
    tile[(bg*2+0)*64 + d] = a0;
    tile[(bg*2+1)*64 + d] = a1;
    __syncthreads();
    for (int jj=0;jj<2;jj++){
      int b = bg*2+jj;
      float v = tile[b*64+d];
      float rot = (d<32)? -tile[b*64+d+32] : tile[b*64+d-32];
      qp[(b*NH+h)*DR + d] = v*cosp[b*DR+d] + rot*sinp[b*DR+d];
    }
  } else if (kind==2){
    qi[(bg*2+0)*1024 + col] = a0;
    qi[(bg*2+1)*1024 + col] = a1;
  } else {
    if (lane<8){
      hw[(bg*2+0)*NIH + lane] = a0;
      hw[(bg*2+1)*NIH + lane] = a1;
    }
  }
}

// ---------- 4. q_lat = q_nope · w_uk ----------
// grid (16 h, 4 col-tiles), 256 thr
__global__ void k_qlat(const float* __restrict__ qn, const float* __restrict__ wuk,
                       float* __restrict__ ql){
  int h = blockIdx.x, ct = blockIdx.y, t = threadIdx.x;
  __shared__ float qs[16*128];
  for (int idx=t; idx<2048; idx+=256)
    qs[idx] = qn[((idx>>7)*NH + h)*DN + (idx&127)];
  int col = ct*128 + (t&127), bg = t>>7;
  __syncthreads();
  float acc[8];
  #pragma unroll
  for (int j=0;j<8;j++) acc[j]=0.f;
  const float* wb = wuk + (size_t)(h*DN)*KVL + col;
  for (int d=0; d<DN; d++){
    float wv = wb[(size_t)d*KVL];
    #pragma unroll
    for (int j=0;j<8;j++) acc[j] += qs[(bg*8+j)*DN + d]*wv;
  }
  #pragma unroll
  for (int j=0;j<8;j++) ql[((bg*8+j)*NH+h)*KVL + col] = acc[j];
}

// ---------- 5. index scores ----------
// grid (16, 32), 256 thr
__global__ void k_isc(const float* __restrict__ qi, const float* __restrict__ hw,
                      const float* __restrict__ ikc, const int* __restrict__ btab,
                      const int* __restrict__ aseq, float* __restrict__ isc){
  int b=blockIdx.x, jb=blockIdx.y, t=threadIdx.x;
  __shared__ float K[64*129];
  __shared__ float qs[NIH*130];
  __shared__ float hs[NIH];
  __shared__ float red[64*4];
  int blk = btab[b*BPS+jb];
  for (int idx=t; idx<NIH*IDXD; idx+=256){ int h2=idx>>7, d=idx&127; qs[h2*130+d]=qi[b*1024+idx]; }
  if (t<NIH) hs[t]=hw[b*NIH+t];
  const float4* k4 = (const float4*)(ikc + (size_t)blk*BLK*IDXD);
  int as = aseq[b];
  int r = t>>2, hp = t&3;
  for (int half=0; half<2; half++){
    __syncthreads();
    for (int it=0; it<8; it++){
      int idx = it*256 + t;
      int rr = idx>>5, c4 = idx&31;
      float4 v = k4[(half*64+rr)*32 + c4];
      float* dst = &K[rr*129 + c4*4];
      dst[0]=v.x; dst[1]=v.y; dst[2]=v.z; dst[3]=v.w;
    }
    __syncthreads();
    float s0=0.f, s1=0.f;
    const float* Kr = &K[r*129];
    const float* q0 = &qs[hp*130];
    const float* q1 = &qs[(hp+4)*130];
    for (int d=0; d<IDXD; d++){
      float kv = Kr[d];
      s0 += q0[d]*kv; s1 += q1[d]*kv;
    }
    red[r*4+hp] = hs[hp]*fmaxf(s0,0.f) + hs[hp+4]*fmaxf(s1,0.f);
    __syncthreads();
    if (t<64){
      float sc = (red[t*4]+red[t*4+1]+red[t*4+2]+red[t*4+3]) * 0.08838834764831845f;
      int n = jb*BLK + half*64 + t;
      if (n >= as) sc = -1e9f;
      isc[b*MAXKV + n] = sc;
    }
  }
}

// ---------- 6. top-1024 via 4-pass radix select + parallel scans ----------
__global__ void k_topk(const float* __restrict__ isc, const int* __restrict__ btab,
                       int* __restrict__ selp, float* __restrict__ sels){
  int b=blockIdx.x, t=threadIdx.x;   // 256
  __shared__ u32 su[MAXKV];
  __shared__ u32 hist[256];
  __shared__ u32 cum[256];
  __shared__ u32 scan[256];
  __shared__ u32 sh_b;
  for (int k2=0;k2<16;k2++){
    int i=k2*256+t;
    u32 bits=__float_as_uint(isc[b*MAXKV+i]);
    su[i] = (bits & 0x80000000u) ? ~bits : (bits | 0x80000000u);
  }
  u32 prefix=0u, need=1024u;
  for (int shift=24; shift>=0; shift-=8){
    hist[t]=0u;
    __syncthreads();
    u32 hm = (shift==24)? 0u : (0xFFFFFFFFu << (shift+8));
    for (int j=0;j<16;j++){
      u32 u = su[t*16+j];
      if ((u & hm) == prefix) atomicAdd(&hist[(u>>shift)&255u], 1u);
    }
    __syncthreads();
    u32 v = hist[t];
    cum[t]=v;
    __syncthreads();
    for (int off=1; off<256; off<<=1){
      u32 w = (t+off<256)? cum[t+off] : 0u;
      __syncthreads();
      v += w; cum[t]=v;
      __syncthreads();
    }
    u32 above = (t<255)? cum[t+1] : 0u;
    if (cum[t] >= need && above < need) sh_b = (u32)t;
    __syncthreads();
    u32 B = sh_b;
    u32 aboveB = (B<255u)? cum[B+1] : 0u;
    need -= aboveB;
    prefix |= (B<<shift);
    __syncthreads();
  }
  u32 T = prefix;
  u32 cG=0u,cE=0u;
  for (int j=0;j<16;j++){ u32 u=su[t*16+j]; cG += (u>T)?1u:0u; cE += (u==T)?1u:0u; }
  u32 packed = (cG<<16) | cE;
  scan[t]=packed;
  __syncthreads();
  u32 v2 = packed;
  for (int off=1; off<256; off<<=1){
    u32 w = (t>=off)? scan[t-off] : 0u;
    __syncthreads();
    v2 += w; scan[t]=v2;
    __syncthreads();
  }
  u32 total = scan[255];
  u32 excl = v2 - packed;
  u32 mGT = total>>16;
  u32 keepEq = 1024u - mGT;
  u32 gG = excl>>16, gE = excl&0xFFFFu;
  for (int j=0;j<16;j++){
    int i=t*16+j; u32 u=su[i];
    int slot=-1;
    if (u>T) slot=(int)(gG++);
    else if (u==T){ u32 r2=gE++; if (r2<keepEq) slot=(int)(mGT+r2); }
    if (slot>=0){
      int pos = btab[b*BPS + (i>>7)]*BLK + (i&127);
      selp[b*TOPK+slot]=pos;
      sels[b*TOPK+slot]=isc[b*MAXKV+i];
    }
  }
}

// ---------- 7. flash attention over selected: scores + chunk softmax + P·V ----------
// grid (16 b, 8 ch), 256 thr
__global__ void k_flash(const float* __restrict__ qlat, const float* __restrict__ qpe,
                        const float* __restrict__ kvc, const float* __restrict__ krc,
                        const int* __restrict__ selp, const float* __restrict__ sels,
                        float* __restrict__ opart, float* __restrict__ mch,
                        float* __restrict__ lch){
  int b=blockIdx.x, ch=blockIdx.y, t=threadIdx.x;
  __shared__ float K[16*580];        // 37.1 KB (128 f4 kv + 16 f4 kr + pad)
  __shared__ float sS[16*17];        // p values per (h, row)
  __shared__ float sM[16], sL[16], sA[16];
  __shared__ int   sp[128];
  __shared__ float sv[128];
  if (t<128){ sp[t]=selp[b*TOPK+ch*128+t]; sv[t]=sels[b*TOPK+ch*128+t]; }
  if (t<16){ sM[t]=-1e30f; sL[t]=0.f; }
  int h = t>>4, i = t&15;            // score role
  int hg = t>>6, c4 = t&63;          // PV role (4 heads, 2 f4 cols)
  const float4* qc  = (const float4*)(qlat + ((size_t)b*NH+h)*KVL);
  const float4* qp4 = (const float4*)(qpe  + ((size_t)b*NH+h)*DR);
  const float4* kv4 = (const float4*)kvc;
  const float4* kr4 = (const float4*)krc;
  float4 acc[8];
  #pragma unroll
  for (int j=0;j<8;j++){ acc[j].x=0.f; acc[j].y=0.f; acc[j].z=0.f; acc[j].w=0.f; }
  const float scale = 0.07216878364870323f;   // 1/sqrt(192)
  for (int st=0; st<8; st++){
    __syncthreads();                 // prev PV done before restaging
    for (int idx=t; idx<16*128; idx+=256){
      int r=idx>>7, cc=idx&127;
      ((float4*)&K[r*580])[cc] = kv4[(size_t)sp[st*16+r]*128 + cc];
    }
    for (int idx=t; idx<16*16; idx+=256){
      int r=idx>>4, cc=idx&15;
      ((float4*)&K[r*580])[128+cc] = kr4[(size_t)sp[st*16+r]*16 + cc];
    }
    __syncthreads();
    // scores: thread (h, i)
    const float4* Kr4 = (const float4*)&K[i*580];
    float s=0.f;
    for (int v=0; v<128; v++){
      float4 q = qc[v]; float4 kk = Kr4[v];
      s += kk.x*q.x + kk.y*q.y + kk.z*q.z + kk.w*q.w;
    }
    for (int v=0; v<16; v++){
      float4 q = qp4[v]; float4 kk = Kr4[128+v];
      s += kk.x*q.x + kk.y*q.y + kk.z*q.z + kk.w*q.w;
    }
    float val = (sv[st*16+i] > -1e8f)? s*scale : -1e9f;
    // per-h max/sum over the 16 i-lanes (wave-private per h)
    float mx = val;
    for (int mm=1; mm<16; mm<<=1) mx = fmaxf(mx, __shfl_xor(mx, mm, 16));
    float mold = sM[h];
    float mnew = fmaxf(mold, mx);
    float p = expf(val - mnew);
    float psum = p;
    for (int mm=1; mm<16; mm<<=1) psum += __shfl_xor(psum, mm, 16);
    sS[h*17+i] = p;
    if (i==0){
      float al = expf(mold - mnew);
      sA[h] = al;
      sM[h] = mnew;
      sL[h] = sL[h]*al + psum;
    }
    __syncthreads();
    // PV: thread (hg, c4) accumulates 4 heads x 2 f4 cols
    #pragma unroll
    for (int j=0;j<4;j++){
      int hh = hg*4+j;
      float al = sA[hh];
      float4 a0=acc[j*2], a1=acc[j*2+1];
      a0.x*=al; a0.y*=al; a0.z*=al; a0.w*=al;
      a1.x*=al; a1.y*=al; a1.z*=al; a1.w*=al;
      for (int rr=0; rr<16; rr++){
        float pv = sS[hh*17+rr];
        const float4* KrR = (const float4*)&K[rr*580];
        float4 k0 = KrR[c4], k1 = KrR[64+c4];
        a0.x += pv*k0.x; a0.y += pv*k0.y; a0.z += pv*k0.z; a0.w += pv*k0.w;
        a1.x += pv*k1.x; a1.y += pv*k1.y; a1.z += pv*k1.z; a1.w += pv*k1.w;
      }
      acc[j*2]=a0; acc[j*2+1]=a1;
    }
  }
  __syncthreads();
  #pragma unroll
  for (int j=0;j<4;j++){
    int hh = hg*4+j;
    float4* dst = (float4*)(opart + (((size_t)(b*8+ch))*NH + hh)*KVL);
    dst[c4]    = acc[j*2];
    dst[64+c4] = acc[j*2+1];
  }
  if (t<16){
    mch[(b*8+ch)*16 + t] = sM[t];
    lch[(b*8+ch)*16 + t] = sL[t];
  }
}

// ---------- 8. combine chunks + project with w_uk ----------
// grid (16 b, 16 h), 128 thr
__global__ void k_comb(const float* __restrict__ opart, const float* __restrict__ mch,
                       const float* __restrict__ lch, const float* __restrict__ wuk,
                       float* __restrict__ out){
  int b=blockIdx.x, h=blockIdx.y, t=threadIdx.x;
  __shared__ float sOl[KVL];
  __shared__ float sCoef[8];
  __shared__ float sInvL;
  if (t==0){
    float mv[8], lv[8], M=-1e30f;
    for (int ch=0;ch<8;ch++){
      mv[ch]=mch[(b*8+ch)*16+h]; lv[ch]=lch[(b*8+ch)*16+h];
      M = fmaxf(M, mv[ch]);
    }
    float L=0.f;
    for (int ch=0;ch<8;ch++){
      float c = expf(mv[ch]-M);
      sCoef[ch]=c; L += lv[ch]*c;
    }
    sInvL = 1.0f/L;
  }
  __syncthreads();
  for (int c=t; c<KVL; c+=128){
    float s=0.f;
    for (int ch=0;ch<8;ch++)
      s += opart[(((size_t)(b*8+ch))*NH + h)*KVL + c] * sCoef[ch];
    sOl[c] = s*sInvL;
  }
  __syncthreads();
  const float4* w4 = (const float4*)(wuk + ((size_t)(h*DN)+t)*KVL);
  const float4* o4 = (const float4*)sOl;
  float a=0.f;
  for (int v=0; v<128; v++){
    float4 w = w4[v]; float4 o = o4[v];
    a += w.x*o.x + w.y*o.y + w.z*o.z + w.w*o.w;
  }
  out[b*(NH*DN) + h*DN + t] = a;
}

extern "C" void kernel_launch(void* const* d_in, const int* in_sizes, int n_in,
                              void* d_out, int out_size, void* d_ws, size_t ws_size,
                              hipStream_t stream){
  const float* x        =(const float*)d_in[0];
  const float* w_dq     =(const float*)d_in[1];
  const float* w_uq_qr  =(const float*)d_in[2];
  const float* w_uk     =(const float*)d_in[3];
  const float* w_dkv_kr =(const float*)d_in[4];
  const float* g_cq     =(const float*)d_in[5];
  const float* g_ckv    =(const float*)d_in[6];
  const float* sinp     =(const float*)d_in[7];
  const float* cosp     =(const float*)d_in[8];
  const int*   cidx     =(const int*)d_in[9];
  float*       kvc      =(float*)d_in[10];
  float*       krc      =(float*)d_in[11];
  const int*   btab     =(const int*)d_in[12];
  const int*   aseq     =(const int*)d_in[13];
  const float* w_idx_qb =(const float*)d_in[14];
  const float* w_idx_k  =(const float*)d_in[15];
  const float* w_idx_pj =(const float*)d_in[16];
  const float* g_ik     =(const float*)d_in[17];
  const float* b_ik     =(const float*)d_in[18];
  float*       ikc      =(float*)d_in[19];

  float* ws    = (float*)d_ws;
  float* cq    = ws;                   // 12288
  float* qpe   = ws + 12288;           // 16384
  float* qnope = ws + 28672;           // 32768
  float* qlat  = ws + 61440;           // 131072
  float* qi    = ws + 192512;          // 16384
  float* hw    = ws + 208896;          // 128
  float* isc   = ws + 209024;          // 65536
  int*   selp  = (int*)(ws + 274560);  // 16384
  float* sels  = ws + 290944;          // 16384
  float* opart = ws + 307328;          // 1048576
  float* mch   = ws + 1355904;         // 2048
  float* lch   = ws + 1357952;         // 2048
  float* dpart = ws + 307328;          // aliases opart (dead before k_flash)

  k_dproj<<<dim3(23,4),   dim3(512),0,stream>>>(x,w_dq,w_dkv_kr,w_idx_k,dpart);
  k_dfin <<<dim3(BS),     dim3(256),0,stream>>>(dpart,g_cq,g_ckv,sinp,cosp,g_ik,b_ik,cidx,cq,kvc,krc,ikc);
  k_qall <<<dim3(65),     dim3(512),0,stream>>>(cq,w_uq_qr,w_idx_qb,w_idx_pj,sinp,cosp,qnope,qpe,qi,hw);
  k_qlat <<<dim3(16,4),   dim3(256),0,stream>>>(qnope,w_uk,qlat);
  k_isc  <<<dim3(BS,BPS), dim3(256),0,stream>>>(qi,hw,ikc,btab,aseq,isc);
  k_topk <<<dim3(BS),     dim3(256),0,stream>>>(isc,btab,selp,sels);
  k_flash<<<dim3(BS,8),   dim3(256),0,stream>>>(qlat,qpe,kvc,krc,selp,sels,opart,mch,lch);
  k_comb <<<dim3(BS,NH),  dim3(128),0,stream>>>(opart,mch,lch,w_uk,(float*)d_out);
}

// Round 5
// 397.670 us; speedup vs baseline: 1.4821x; 1.4821x over previous
//
#include <hip/hip_runtime.h>

typedef unsigned int u32;

#define BS    16
#define HDIM  2048
#define QL    768
#define KVL   512
#define DR    64
#define DN    128
#define NH    16
#define NIH   8
#define IDXD  128
#define BLK   128
#define BPS   32
#define MAXKV 4096
#define TOPK  1024
#define NCH   32            // flash chunks per batch (32 rows each)

// ---------- 1. down-proj partials: cols [0:768|768:1344|1344:1472] ----------
// grid (46 col-tiles of 32, 16 k-splits of 128), 256 thr = 32 cols x 8 kgroups
__global__ void k_dproj(const float* __restrict__ x, const float* __restrict__ w_dq,
                        const float* __restrict__ w_dkv, const float* __restrict__ w_ik,
                        float* __restrict__ dpart){
  int tile = blockIdx.x, ks = blockIdx.y, t = threadIdx.x;
  __shared__ float xs[16*128];          // 8 KB
  __shared__ float sred[8*32*17];       // 17 KB, padded
  int k0 = ks*128;
  for (int idx=t; idx<16*128; idx+=256){
    int bb=idx>>7, kk=idx&127;
    xs[idx] = x[bb*HDIM + k0 + kk];
  }
  const float* wp; int ld, c0, gbase;
  if (tile < 24){ wp=w_dq;  ld=768; c0=tile*32;      gbase=0; }
  else if (tile < 42){ wp=w_dkv; ld=576; c0=(tile-24)*32; gbase=768; }
  else { wp=w_ik;  ld=128; c0=(tile-42)*32; gbase=1344; }
  int cl = t&31, kg = t>>5;
  int col = c0 + cl;
  __syncthreads();
  float acc[16];
  #pragma unroll
  for (int bb=0;bb<16;bb++) acc[bb]=0.f;
  const float* wb = wp + (size_t)(k0 + kg*16)*ld + col;
  #pragma unroll 4
  for (int kk=0; kk<16; kk++){
    float wv = wb[(size_t)kk*ld];
    int kx = kg*16+kk;
    #pragma unroll
    for (int bb=0; bb<16; bb++) acc[bb] += xs[bb*128+kx]*wv;
  }
  #pragma unroll
  for (int bb=0;bb<16;bb++) sred[(kg*32+cl)*17+bb] = acc[bb];
  __syncthreads();
  for (int r=0; r<2; r++){
    int o = r*256 + t;
    int bb = o>>5, cl2 = o&31;
    float s=0.f;
    #pragma unroll
    for (int kg2=0; kg2<8; kg2++) s += sred[(kg2*32+cl2)*17+bb];
    dpart[((size_t)ks*16 + bb)*1472 + gbase + c0 + cl2] = s;
  }
}

// ---------- 2. finalize norms + cache scatter ----------
__global__ void k_dfin(const float* __restrict__ dpart, const float* __restrict__ g_cq,
                       const float* __restrict__ g_ckv, const float* __restrict__ sinp,
                       const float* __restrict__ cosp, const float* __restrict__ g_ik,
                       const float* __restrict__ b_ik, const int* __restrict__ cidx,
                       float* __restrict__ cq, float* __restrict__ kvc,
                       float* __restrict__ krc, float* __restrict__ ikc){
  int b = blockIdx.x, t = threadIdx.x;   // 256
  __shared__ float val[1472];
  __shared__ float red[256];
  for (int c=t; c<1472; c+=256){
    float s = 0.f;
    for (int ks2=0; ks2<16; ks2++) s += dpart[((size_t)ks2*16+b)*1472 + c];
    val[c] = s;
  }
  __syncthreads();
  float c0v = val[t], c1v = val[t+256], c2v = val[t+512];
  red[t] = c0v*c0v + c1v*c1v + c2v*c2v;
  __syncthreads();
  for (int s=128;s>0;s>>=1){ if(t<s) red[t]+=red[t+s]; __syncthreads(); }
  float scq = 1.0f/sqrtf(red[0]/(float)QL + 1e-6f);
  __syncthreads();
  float v0 = val[768+t], v1 = val[1024+t];
  red[t] = v0*v0 + v1*v1;
  __syncthreads();
  for (int s=128;s>0;s>>=1){ if(t<s) red[t]+=red[t+s]; __syncthreads(); }
  float sckv = 1.0f/sqrtf(red[0]/(float)KVL + 1e-6f);
  __syncthreads();
  red[t] = (t<128)? val[1344+t] : 0.f;
  __syncthreads();
  for (int s=128;s>0;s>>=1){ if(t<s) red[t]+=red[t+s]; __syncthreads(); }
  float mean = red[0]/(float)IDXD;
  __syncthreads();
  float cc = (t<128)? (val[1344+t]-mean) : 0.f;
  red[t] = cc*cc;
  __syncthreads();
  for (int s=128;s>0;s>>=1){ if(t<s) red[t]+=red[t+s]; __syncthreads(); }
  float var = red[0]/(float)IDXD;
  int ci = cidx[b];
  cq[b*QL+t]     = c0v*scq*g_cq[t];
  cq[b*QL+t+256] = c1v*scq*g_cq[t+256];
  cq[b*QL+t+512] = c2v*scq*g_cq[t+512];
  kvc[(size_t)ci*KVL + t]     = v0*sckv*g_ckv[t];
  kvc[(size_t)ci*KVL + t+256] = v1*sckv*g_ckv[t+256];
  if (t<DR){
    float v = val[1280+t];
    float rot = (t<32)? -val[1280+t+32] : val[1280+t-32];
    krc[(size_t)ci*DR + t] = v*cosp[b*DR+t] + rot*sinp[b*DR+t];
  }
  if (t<IDXD){
    ikc[(size_t)ci*IDXD + t] = cc/sqrtf(var+1e-6f)*g_ik[t] + b_ik[t];
  }
}

// ---------- 3. q-level proj partials (w_uq_qr | w_idx_qb | w_idx_proj) ----------
// grid (129 col-tiles, 4 k-splits of 192), 256 thr = 32 cols x 8 kgroups of 24
__global__ void k_qall(const float* __restrict__ cq, const float* __restrict__ w_uq,
                       const float* __restrict__ w_qb, const float* __restrict__ w_pj,
                       float* __restrict__ qpart){
  int tile = blockIdx.x, ks = blockIdx.y, t = threadIdx.x;
  __shared__ float xs[16*192];          // 12 KB
  __shared__ float sred[8*32*17];       // 17 KB
  int k0 = ks*192;
  for (int idx=t; idx<16*192; idx+=256){
    int bb = idx/192, kk = idx - bb*192;
    xs[idx] = cq[bb*QL + k0 + kk];
  }
  const float* wp; int ld, c0, gbase, kind;
  if (tile < 96){ wp=w_uq; ld=3072; c0=tile*32; gbase=0; kind=0; }
  else if (tile < 128){ wp=w_qb; ld=1024; c0=(tile-96)*32; gbase=3072; kind=0; }
  else { wp=w_pj; ld=8; c0=0; gbase=4096; kind=1; }
  int cl = t&31, kg = t>>5;
  int col = c0 + cl;
  bool act = !(kind==1 && cl>=8);
  __syncthreads();
  float acc[16];
  #pragma unroll
  for (int bb=0;bb<16;bb++) acc[bb]=0.f;
  const float* wb = wp + (size_t)(k0 + kg*24)*ld + col;
  if (act){
    #pragma unroll 4
    for (int kk=0; kk<24; kk++){
      float wv = wb[(size_t)kk*ld];
      int kx = kg*24+kk;
      #pragma unroll
      for (int bb=0; bb<16; bb++) acc[bb] += xs[bb*192+kx]*wv;
    }
  }
  #pragma unroll
  for (int bb=0;bb<16;bb++) sred[(kg*32+cl)*17+bb] = acc[bb];
  __syncthreads();
  for (int r=0; r<2; r++){
    int o = r*256 + t;
    int bb = o>>5, cl2 = o&31;
    float s=0.f;
    #pragma unroll
    for (int kg2=0; kg2<8; kg2++) s += sred[(kg2*32+cl2)*17+bb];
    qpart[((size_t)ks*16 + bb)*4128 + gbase + c0 + cl2] = s;
  }
}

// ---------- 4. finalize q-level: sum partials, rope, split ----------
__global__ void k_qfin(const float* __restrict__ qpart, const float* __restrict__ sinp,
                       const float* __restrict__ cosp, float* __restrict__ qn,
                       float* __restrict__ qp, float* __restrict__ qi,
                       float* __restrict__ hw){
  int b=blockIdx.x, t=threadIdx.x;   // 256
  __shared__ float val[4104];
  for (int c=t; c<4104; c+=256){
    float s=0.f;
    for (int ks=0; ks<4; ks++) s += qpart[((size_t)ks*16+b)*4128 + c];
    val[c]=s;
  }
  __syncthreads();
  for (int c=t; c<4104; c+=256){
    if (c<3072){
      int h=c/192, j=c-h*192;
      if (j<128) qn[(b*NH+h)*DN+j] = val[c];
      else {
        int d=j-128;
        float v=val[c];
        float rot = (d<32)? -val[h*192+160+d] : val[h*192+96+d];
        qp[(b*NH+h)*DR+d] = v*cosp[b*DR+d] + rot*sinp[b*DR+d];
      }
    } else if (c<4096){
      qi[b*1024 + c-3072] = val[c];
    } else {
      hw[b*NIH + c-4096] = val[c];
    }
  }
}

// ---------- 5. q_lat = q_nope · w_uk ----------
// grid (16 h, 8 col-tiles of 64), 256 thr = 64 cols x 4 kgroups of 32
__global__ void k_qlat(const float* __restrict__ qn, const float* __restrict__ wuk,
                       float* __restrict__ ql){
  int h=blockIdx.x, ct=blockIdx.y, t=threadIdx.x;
  __shared__ float qs[16*128];          // 8 KB
  __shared__ float sred[4*64*17];       // 17.4 KB
  for (int idx=t; idx<2048; idx+=256)
    qs[idx] = qn[((idx>>7)*NH+h)*DN + (idx&127)];
  int cl=t&63, kg=t>>6;
  int col=ct*64+cl;
  __syncthreads();
  float acc[16];
  #pragma unroll
  for (int bb=0;bb<16;bb++) acc[bb]=0.f;
  const float* wb = wuk + ((size_t)h*DN + kg*32)*KVL + col;
  #pragma unroll 4
  for (int kk=0;kk<32;kk++){
    float wv = wb[(size_t)kk*KVL];
    int kx = kg*32+kk;
    #pragma unroll
    for (int bb=0;bb<16;bb++) acc[bb]+=qs[bb*128+kx]*wv;
  }
  #pragma unroll
  for (int bb=0;bb<16;bb++) sred[(kg*64+cl)*17+bb]=acc[bb];
  __syncthreads();
  for (int r=0;r<4;r++){
    int o=r*256+t;
    int bb=o>>6, cl2=o&63;
    float s=0.f;
    #pragma unroll
    for (int kg2=0;kg2<4;kg2++) s+=sred[(kg2*64+cl2)*17+bb];
    ql[((size_t)bb*NH+h)*KVL + ct*64+cl2] = s;
  }
}

// ---------- 6. index scores ----------
// grid (16, 32), 256 thr
__global__ void k_isc(const float* __restrict__ qi, const float* __restrict__ hw,
                      const float* __restrict__ ikc, const int* __restrict__ btab,
                      const int* __restrict__ aseq, float* __restrict__ isc){
  int b=blockIdx.x, jb=blockIdx.y, t=threadIdx.x;
  __shared__ float K[64*129];
  __shared__ float qs[NIH*130];
  __shared__ float hs[NIH];
  __shared__ float red[64*4];
  int blk = btab[b*BPS+jb];
  for (int idx=t; idx<NIH*IDXD; idx+=256){ int h2=idx>>7, d=idx&127; qs[h2*130+d]=qi[b*1024+idx]; }
  if (t<NIH) hs[t]=hw[b*NIH+t];
  const float4* k4 = (const float4*)(ikc + (size_t)blk*BLK*IDXD);
  int as = aseq[b];
  int r = t>>2, hp = t&3;
  for (int half=0; half<2; half++){
    __syncthreads();
    for (int it=0; it<8; it++){
      int idx = it*256 + t;
      int rr = idx>>5, c4 = idx&31;
      float4 v = k4[(half*64+rr)*32 + c4];
      float* dst = &K[rr*129 + c4*4];
      dst[0]=v.x; dst[1]=v.y; dst[2]=v.z; dst[3]=v.w;
    }
    __syncthreads();
    float s0=0.f, s1=0.f;
    const float* Kr = &K[r*129];
    const float* q0 = &qs[hp*130];
    const float* q1 = &qs[(hp+4)*130];
    for (int d=0; d<IDXD; d++){
      float kv = Kr[d];
      s0 += q0[d]*kv; s1 += q1[d]*kv;
    }
    red[r*4+hp] = hs[hp]*fmaxf(s0,0.f) + hs[hp+4]*fmaxf(s1,0.f);
    __syncthreads();
    if (t<64){
      float sc = (red[t*4]+red[t*4+1]+red[t*4+2]+red[t*4+3]) * 0.08838834764831845f;
      int n = jb*BLK + half*64 + t;
      if (n >= as) sc = -1e9f;
      isc[b*MAXKV + n] = sc;
    }
  }
}

// ---------- 7. top-1024: radix select with wave-shuffle scans ----------
__global__ void k_topk(const float* __restrict__ isc, const int* __restrict__ btab,
                       int* __restrict__ selp, float* __restrict__ sels){
  int b=blockIdx.x, t=threadIdx.x;   // 256 thr = 4 waves
  int lane = t&63, wv = t>>6;
  __shared__ u32 su[MAXKV];          // 16 KB
  __shared__ u32 hist[256];
  __shared__ u32 cum[256];
  __shared__ u32 wtot[4];
  __shared__ u32 sh_b;
  for (int k2=0;k2<16;k2++){
    int i=k2*256+t;
    u32 bits=__float_as_uint(isc[b*MAXKV+i]);
    su[i] = (bits & 0x80000000u) ? ~bits : (bits | 0x80000000u);
  }
  u32 prefix=0u, need=1024u;
  for (int shift=24; shift>=0; shift-=8){
    hist[t]=0u;
    __syncthreads();
    u32 hm = (shift==24)? 0u : (0xFFFFFFFFu << (shift+8));
    for (int j=0;j<16;j++){
      u32 u = su[t*16+j];
      if ((u & hm) == prefix) atomicAdd(&hist[(u>>shift)&255u], 1u);
    }
    __syncthreads();
    // suffix-sum of hist: cum[i] = sum_{j>=i} hist[j]
    u32 v = hist[wv*64+lane];
    for (int off=1; off<64; off<<=1){
      u32 tmp = __shfl_down(v, off);
      if (lane + off < 64) v += tmp;
    }
    if (lane==0) wtot[wv]=v;
    __syncthreads();
    u32 add=0u;
    for (int w2=wv+1; w2<4; w2++) add += wtot[w2];
    v += add;
    cum[wv*64+lane] = v;
    __syncthreads();
    int bin = wv*64+lane;
    u32 nxt = (bin<255)? cum[bin+1] : 0u;
    if (v>=need && nxt<need) sh_b = (u32)bin;
    __syncthreads();
    u32 B = sh_b;
    u32 aboveB = (B<255u)? cum[B+1] : 0u;
    need -= aboveB;
    prefix |= (B<<shift);
    __syncthreads();
  }
  u32 T = prefix;
  u32 cG=0u,cE=0u;
  for (int j=0;j<16;j++){ u32 u=su[t*16+j]; cG += (u>T)?1u:0u; cE += (u==T)?1u:0u; }
  u32 packed = (cG<<16) | cE;
  u32 v = packed;
  for (int off=1; off<64; off<<=1){
    u32 tmp = __shfl_up(v, off);
    if (lane >= off) v += tmp;
  }
  if (lane==63) wtot[wv]=v;
  __syncthreads();
  u32 add=0u;
  for (int w2=0; w2<wv; w2++) add += wtot[w2];
  u32 excl = v + add - packed;
  u32 total = wtot[0]+wtot[1]+wtot[2]+wtot[3];
  u32 mGT = total>>16;
  u32 keepEq = 1024u - mGT;
  u32 gG = excl>>16, gE = excl&0xFFFFu;
  for (int j=0;j<16;j++){
    int i=t*16+j; u32 u=su[i];
    int slot=-1;
    if (u>T) slot=(int)(gG++);
    else if (u==T){ u32 r2=gE++; if (r2<keepEq) slot=(int)(mGT+r2); }
    if (slot>=0){
      int pos = btab[b*BPS + (i>>7)]*BLK + (i&127);
      selp[b*TOPK+slot]=pos;
      sels[b*TOPK+slot]=isc[b*MAXKV+i];
    }
  }
}

// ---------- 8. fused gather attention: scores + chunk softmax + P·V ----------
// grid (16 b, 32 ch of 32 rows), 256 thr; 2 stages of 16 rows
__global__ void k_fgat(const float* __restrict__ qlat, const float* __restrict__ qpe,
                       const float* __restrict__ kvc, const float* __restrict__ krc,
                       const int* __restrict__ selp, const float* __restrict__ sels,
                       float* __restrict__ opart, float* __restrict__ mch,
                       float* __restrict__ lch){
  int b=blockIdx.x, ch=blockIdx.y, t=threadIdx.x;
  __shared__ float K[16*580];        // 37.1 KB
  __shared__ float sS[16*17];
  __shared__ float sM[16], sL[16], sA[16];
  __shared__ int   sp[32];
  __shared__ float sv[32];
  if (t<32){ sp[t]=selp[b*TOPK+ch*32+t]; sv[t]=sels[b*TOPK+ch*32+t]; }
  if (t<16){ sM[t]=-1e30f; sL[t]=0.f; }
  int h = t>>4, i = t&15;            // score role
  int hg = t>>6, c4 = t&63;          // PV role
  const float4* qc  = (const float4*)(qlat + ((size_t)b*NH+h)*KVL);
  const float4* qp4 = (const float4*)(qpe  + ((size_t)b*NH+h)*DR);
  const float4* kv4 = (const float4*)kvc;
  const float4* kr4 = (const float4*)krc;
  float4 acc[8];
  #pragma unroll
  for (int j=0;j<8;j++){ acc[j].x=0.f; acc[j].y=0.f; acc[j].z=0.f; acc[j].w=0.f; }
  const float scale = 0.07216878364870323f;   // 1/sqrt(192)
  for (int st=0; st<2; st++){
    __syncthreads();
    for (int idx=t; idx<16*128; idx+=256){
      int r=idx>>7, cc=idx&127;
      ((float4*)&K[r*580])[cc] = kv4[(size_t)sp[st*16+r]*128 + cc];
    }
    for (int idx=t; idx<16*16; idx+=256){
      int r=idx>>4, cc=idx&15;
      ((float4*)&K[r*580])[128+cc] = kr4[(size_t)sp[st*16+r]*16 + cc];
    }
    __syncthreads();
    const float4* Kr4 = (const float4*)&K[i*580];
    float s=0.f;
    for (int v=0; v<128; v++){
      float4 q = qc[v]; float4 kk = Kr4[v];
      s += kk.x*q.x + kk.y*q.y + kk.z*q.z + kk.w*q.w;
    }
    for (int v=0; v<16; v++){
      float4 q = qp4[v]; float4 kk = Kr4[128+v];
      s += kk.x*q.x + kk.y*q.y + kk.z*q.z + kk.w*q.w;
    }
    float val = (sv[st*16+i] > -1e8f)? s*scale : -1e9f;
    float mx = val;
    for (int mm=1; mm<16; mm<<=1) mx = fmaxf(mx, __shfl_xor(mx, mm, 16));
    float mold = sM[h];
    float mnew = fmaxf(mold, mx);
    float p = expf(val - mnew);
    float psum = p;
    for (int mm=1; mm<16; mm<<=1) psum += __shfl_xor(psum, mm, 16);
    sS[h*17+i] = p;
    if (i==0){
      float al = expf(mold - mnew);
      sA[h] = al;
      sM[h] = mnew;
      sL[h] = sL[h]*al + psum;
    }
    __syncthreads();
    #pragma unroll
    for (int j=0;j<4;j++){
      int hh = hg*4+j;
      float al = sA[hh];
      float4 a0=acc[j*2], a1=acc[j*2+1];
      a0.x*=al; a0.y*=al; a0.z*=al; a0.w*=al;
      a1.x*=al; a1.y*=al; a1.z*=al; a1.w*=al;
      for (int rr=0; rr<16; rr++){
        float pv = sS[hh*17+rr];
        const float4* KrR = (const float4*)&K[rr*580];
        float4 k0 = KrR[c4], k1 = KrR[64+c4];
        a0.x += pv*k0.x; a0.y += pv*k0.y; a0.z += pv*k0.z; a0.w += pv*k0.w;
        a1.x += pv*k1.x; a1.y += pv*k1.y; a1.z += pv*k1.z; a1.w += pv*k1.w;
      }
      acc[j*2]=a0; acc[j*2+1]=a1;
    }
  }
  __syncthreads();
  #pragma unroll
  for (int j=0;j<4;j++){
    int hh = hg*4+j;
    float4* dst = (float4*)(opart + (((size_t)(b*NCH+ch))*NH + hh)*KVL);
    dst[c4]    = acc[j*2];
    dst[64+c4] = acc[j*2+1];
  }
  if (t<16){
    mch[(b*NCH+ch)*16 + t] = sM[t];
    lch[(b*NCH+ch)*16 + t] = sL[t];
  }
}

// ---------- 9. combine chunks + project with w_uk ----------
// grid (16 b, 16 h), 128 thr
__global__ void k_comb(const float* __restrict__ opart, const float* __restrict__ mch,
                       const float* __restrict__ lch, const float* __restrict__ wuk,
                       float* __restrict__ out){
  int b=blockIdx.x, h=blockIdx.y, t=threadIdx.x;
  __shared__ float sOl[KVL];
  __shared__ float sCoef[NCH];
  __shared__ float sInvL;
  if (t<NCH){
    float mv = mch[(b*NCH+t)*16+h];
    float lv = lch[(b*NCH+t)*16+h];
    float M = mv;
    for (int off=1; off<NCH; off<<=1) M = fmaxf(M, __shfl_xor(M, off, NCH));
    float coef = expf(mv - M);
    float Lp = lv*coef;
    for (int off=1; off<NCH; off<<=1) Lp += __shfl_xor(Lp, off, NCH);
    sCoef[t] = coef;
    if (t==0) sInvL = 1.0f/Lp;
  }
  __syncthreads();
  for (int c=t; c<KVL; c+=128){
    float s=0.f;
    for (int ch=0; ch<NCH; ch++)
      s += opart[(((size_t)(b*NCH+ch))*NH + h)*KVL + c] * sCoef[ch];
    sOl[c] = s*sInvL;
  }
  __syncthreads();
  const float4* w4 = (const float4*)(wuk + ((size_t)(h*DN)+t)*KVL);
  const float4* o4 = (const float4*)sOl;
  float a=0.f;
  for (int v=0; v<128; v++){
    float4 w = w4[v]; float4 o = o4[v];
    a += w.x*o.x + w.y*o.y + w.z*o.z + w.w*o.w;
  }
  out[b*(NH*DN) + h*DN + t] = a;
}

extern "C" void kernel_launch(void* const* d_in, const int* in_sizes, int n_in,
                              void* d_out, int out_size, void* d_ws, size_t ws_size,
                              hipStream_t stream){
  const float* x        =(const float*)d_in[0];
  const float* w_dq     =(const float*)d_in[1];
  const float* w_uq_qr  =(const float*)d_in[2];
  const float* w_uk     =(const float*)d_in[3];
  const float* w_dkv_kr =(const float*)d_in[4];
  const float* g_cq     =(const float*)d_in[5];
  const float* g_ckv    =(const float*)d_in[6];
  const float* sinp     =(const float*)d_in[7];
  const float* cosp     =(const float*)d_in[8];
  const int*   cidx     =(const int*)d_in[9];
  float*       kvc      =(float*)d_in[10];
  float*       krc      =(float*)d_in[11];
  const int*   btab     =(const int*)d_in[12];
  const int*   aseq     =(const int*)d_in[13];
  const float* w_idx_qb =(const float*)d_in[14];
  const float* w_idx_k  =(const float*)d_in[15];
  const float* w_idx_pj =(const float*)d_in[16];
  const float* g_ik     =(const float*)d_in[17];
  const float* b_ik     =(const float*)d_in[18];
  float*       ikc      =(float*)d_in[19];

  float* ws    = (float*)d_ws;
  float* cq    = ws;                   // 12288
  float* qnope = ws + 12288;           // 32768
  float* qpe   = ws + 45056;           // 16384
  float* qlat  = ws + 61440;           // 131072
  float* qi    = ws + 192512;          // 16384
  float* hw    = ws + 208896;          // 128
  float* isc   = ws + 209024;          // 65536
  int*   selp  = (int*)(ws + 274560);  // 16384
  float* sels  = ws + 290944;          // 16384
  float* dpart = ws + 307328;          // 16*16*1472 = 376832
  float* qpart = ws + 684160;          // 4*16*4128  = 264192
  float* mch   = ws + 948352;          // 16*32*16   = 8192
  float* lch   = ws + 956544;          // 8192
  float* opart = ws + 964736;          // 16*32*16*512 = 4194304

  k_dproj<<<dim3(46,16),  dim3(256),0,stream>>>(x,w_dq,w_dkv_kr,w_idx_k,dpart);
  k_dfin <<<dim3(BS),     dim3(256),0,stream>>>(dpart,g_cq,g_ckv,sinp,cosp,g_ik,b_ik,cidx,cq,kvc,krc,ikc);
  k_qall <<<dim3(129,4),  dim3(256),0,stream>>>(cq,w_uq_qr,w_idx_qb,w_idx_pj,qpart);
  k_qfin <<<dim3(BS),     dim3(256),0,stream>>>(qpart,sinp,cosp,qnope,qpe,qi,hw);
  k_qlat <<<dim3(16,8),   dim3(256),0,stream>>>(qnope,w_uk,qlat);
  k_isc  <<<dim3(BS,BPS), dim3(256),0,stream>>>(qi,hw,ikc,btab,aseq,isc);
  k_topk <<<dim3(BS),     dim3(256),0,stream>>>(isc,btab,selp,sels);
  k_fgat <<<dim3(BS,NCH), dim3(256),0,stream>>>(qlat,qpe,kvc,krc,selp,sels,opart,mch,lch);
  k_comb <<<dim3(BS,NH),  dim3(128),0,stream>>>(opart,mch,lch,w_uk,(float*)d_out);
}